// Round 3
// baseline (234.381 us; speedup 1.0000x reference)
//
#include <hip/hip_runtime.h>
#include <hip/hip_bf16.h>
#include <math.h>

// Problem constants (B,C,L,H fixed by setup_inputs)
#define NB 8
#define NC 512
#define NL 8192
#define NH 128
#define FEPS 1e-5f
#define NKEEP 358   // int(512*0.7)

typedef __attribute__((ext_vector_type(8))) short short8;
typedef __attribute__((ext_vector_type(4))) float f32x4;

__device__ __forceinline__ unsigned short f2bf(float x) {
  unsigned u = __float_as_uint(x);
  return (unsigned short)((u + 0x7fffu + ((u >> 16) & 1u)) >> 16);  // RNE
}
__device__ __forceinline__ unsigned pack2(float a, float b) {
  return (unsigned)f2bf(a) | ((unsigned)f2bf(b) << 16);
}

// ---------------- K1: per-(b,c) sum/sumsq of x over L; blocks 0..255 also prep weights ----------------
// Near-roofline streamer (measured ~5.4 TB/s): 2048+ blocks, no barriers in the stream.
__global__ __launch_bounds__(256) void k1_xstats(
    const float* __restrict__ x, float* __restrict__ xsum, float* __restrict__ xsumsq,
    const float* __restrict__ gw1, const float* __restrict__ gw2,
    unsigned short* __restrict__ gw1b, unsigned short* __restrict__ gw2b,
    float* __restrict__ csum, float* __restrict__ gsum) {
  const int bc = blockIdx.x;
  const int t = threadIdx.x;
  if (bc < 256) {                       // fused weight prep (65536 = H*C = C*H elems)
    const int i = bc * 256 + t;
    gw1b[i] = f2bf(gw1[i]);
    gw2b[i] = f2bf(gw2[i]);
    if (i < NB * NC) { csum[i] = 0.f; gsum[i] = 0.f; }
  }
  const float4* xp = reinterpret_cast<const float4*>(x + (size_t)bc * NL);
  float s1 = 0.f, s2 = 0.f;
#pragma unroll
  for (int i = 0; i < 8; ++i) {
    float4 v = xp[i * 256 + t];
    s1 += v.x + v.y + v.z + v.w;
    s2 += v.x * v.x + v.y * v.y + v.z * v.z + v.w * v.w;
  }
  for (int off = 32; off; off >>= 1) { s1 += __shfl_down(s1, off); s2 += __shfl_down(s2, off); }
  __shared__ float r1[4], r2[4];
  if ((t & 63) == 0) { r1[t >> 6] = s1; r2[t >> 6] = s2; }
  __syncthreads();
  if (t == 0) {
    xsum[bc]   = r1[0] + r1[1] + r1[2] + r1[3];
    xsumsq[bc] = r2[0] + r2[1] + r2[2] + r2[3];
  }
}

// ---------------- K2: gate network; 4 independent blocks/CU to fill drain windows ----------------
// Diagnosis: k2 is a fixed-rate streamer limited by loads-in-flight duty cycle
// (134MB/78us = 1.7 TB/s vs k1's 5.4 TB/s). Fix = block-level asynchrony:
// l-tile 64, grid 1024, LDS 25KB -> 4 blocks/CU; 4 waves, wave owns 16 l-rows.
// GEMM1 (K=512, 8 chunks BK=64): A = transposed c (fp32->bf16) LDS dbuf, nt
//   prefetch 1 chunk ahead; B-frags (bfr[16] regs) issued BEFORE the nt prefetch
//   (vmcnt is in-order: MFMA waits then cover only the L2 bfr loads, never the
//   HBM prefetch), pinned with sched_barrier.
// GEMM2 (K=128): B-frag = contiguous 16B of gw2b row direct from L2, barrier-free.
// Hts (H^T transpose buffer) aliases the dead A-dbuf after GEMM1's last barrier.
__global__ __launch_bounds__(256, 4) void k2_gate(
    const float* __restrict__ cin,
    const unsigned short* __restrict__ gw1b, const unsigned short* __restrict__ gw2b,
    const float* __restrict__ gb1, const float* __restrict__ gb2,
    float* __restrict__ gsum_g, float* __restrict__ csum_g) {
  __shared__ __align__(16) unsigned AsU[2 * 64 * 36];   // 18432B; aliased by Hts[4][16][136] (17408B) after GEMM1
  __shared__ float gsum_s[NC], csum_s[NC], gb2_s[NC];
  __shared__ float gb1_s[NH];

  const int t = threadIdx.x;
  const int lane = t & 63;
  const int w = t >> 6;                 // 0..3
  const int r = lane & 15;
  const int kg = lane >> 4;
  const int b = blockIdx.x >> 7;        // 128 l-tiles per batch
  const int l0 = (blockIdx.x & 127) * 64;

  // A staging roles: p = chpair 0..31, q = quad 0..7
  const int p = t >> 3;
  const int q = t & 7;

  f32x4 acc[8];
#pragma unroll
  for (int i = 0; i < 8; ++i) acc[i] = (f32x4){0.f,0.f,0.f,0.f};

  const float* cbase = cin + (size_t)b * NC * NL + l0;
  const unsigned short* gw1r = gw1b + (size_t)r * NC + kg * 8;   // + ht*16*NC + k*64 + kk*32

  f32x4 va[2], vb[2];

#define LOADA(kch) { \
    _Pragma("unroll") \
    for (int pass = 0; pass < 2; ++pass) { \
      const float* cp0 = cbase + (size_t)((kch) * 64 + 2 * p) * NL + 32 * pass + 4 * q; \
      va[pass] = __builtin_nontemporal_load(reinterpret_cast<const f32x4*>(cp0)); \
      vb[pass] = __builtin_nontemporal_load(reinterpret_cast<const f32x4*>(cp0 + NL)); \
    } }

#define WRITEA(kch, bufi) { \
    unsigned* dst = AsU + (bufi) * (64 * 36); \
    float sa = 0.f, sb = 0.f; \
    _Pragma("unroll") \
    for (int pass = 0; pass < 2; ++pass) { \
      const int ll = 32 * pass + 4 * q; \
      sa += va[pass].x + va[pass].y + va[pass].z + va[pass].w; \
      sb += vb[pass].x + vb[pass].y + vb[pass].z + vb[pass].w; \
      dst[(ll + 0) * 36 + p] = pack2(va[pass].x, vb[pass].x); \
      dst[(ll + 1) * 36 + p] = pack2(va[pass].y, vb[pass].y); \
      dst[(ll + 2) * 36 + p] = pack2(va[pass].z, vb[pass].z); \
      dst[(ll + 3) * 36 + p] = pack2(va[pass].w, vb[pass].w); \
    } \
    sa += __shfl_xor(sa, 1); sa += __shfl_xor(sa, 2); sa += __shfl_xor(sa, 4); \
    sb += __shfl_xor(sb, 1); sb += __shfl_xor(sb, 2); sb += __shfl_xor(sb, 4); \
    if ((lane & 7) == 0) { \
      csum_s[(kch) * 64 + 2 * p]     = sa; \
      csum_s[(kch) * 64 + 2 * p + 1] = sb; \
    } }

  // prologue: issue chunk-0 loads first, init smem, barrier, stage chunk 0
  LOADA(0)
  for (int i = t; i < NC; i += 256) { gsum_s[i] = 0.f; gb2_s[i] = gb2[i]; }
  if (t < NH) gb1_s[t] = gb1[t];
  __syncthreads();
  WRITEA(0, 0)
  __syncthreads();

  // ---------------- GEMM1 main loop: one barrier per K-chunk ----------------
  for (int k = 0; k < 8; ++k) {
    // B-frags FIRST (older in vmcnt queue than the nt prefetch)
    short8 bfr[16];
#pragma unroll
    for (int ht = 0; ht < 8; ++ht) {
      bfr[2 * ht]     = *reinterpret_cast<const short8*>(gw1r + (size_t)(ht * 16) * NC + k * 64);
      bfr[2 * ht + 1] = *reinterpret_cast<const short8*>(gw1r + (size_t)(ht * 16) * NC + k * 64 + 32);
    }
    __builtin_amdgcn_sched_barrier(0);
    if (k < 7) LOADA(k + 1)               // HBM nt prefetch, stays in flight through MFMA
    __builtin_amdgcn_sched_barrier(0);
    const unsigned* Abuf = AsU + (k & 1) * (64 * 36);
#pragma unroll
    for (int kk = 0; kk < 2; ++kk) {
      const short8 a = *reinterpret_cast<const short8*>(&Abuf[(16 * w + r) * 36 + 16 * kk + 4 * kg]);
#pragma unroll
      for (int ht = 0; ht < 8; ++ht)
        acc[ht] = __builtin_amdgcn_mfma_f32_16x16x32_bf16(a, bfr[2 * ht + kk], acc[ht], 0, 0, 0);
    }
    if (k < 7) WRITEA(k + 1, (k + 1) & 1) // vmcnt(0) lands here, after MFMAs issued
    __syncthreads();
  }

  // epilogue: bias+relu -> Hts (aliases AsU; safe: loop ended with __syncthreads)
  // D map: col=lane&15 -> h, row=(lane>>4)*4+reg -> l-local
  unsigned short (*Hts)[16][136] = reinterpret_cast<unsigned short (*)[16][136]>(AsU);
#pragma unroll
  for (int ht = 0; ht < 8; ++ht) {
    const float bias = gb1_s[16 * ht + r];
#pragma unroll
    for (int reg = 0; reg < 4; ++reg)
      Hts[w][4 * kg + reg][16 * ht + r] = f2bf(fmaxf(acc[ht][reg] + bias, 0.f));
  }
  // wave-local write->read: per-wave region, no barrier needed
  short8 af[4];
#pragma unroll
  for (int kk = 0; kk < 4; ++kk)
    af[kk] = *reinterpret_cast<const short8*>(&Hts[w][r][32 * kk + 8 * kg]);

  // ---------------- GEMM2: gsum[c] += sigmoid(H^T . gw2[c] + gb2), B direct from L2, barrier-free ----
  const unsigned short* gw2r = gw2b + (size_t)r * NH + kg * 8;   // + (cc*64+16*ctt)*NH + kk*32
  for (int cc = 0; cc < 8; ++cc) {
#pragma unroll
    for (int ctt = 0; ctt < 4; ++ctt) {
      f32x4 z = (f32x4){0.f,0.f,0.f,0.f};
#pragma unroll
      for (int kk = 0; kk < 4; ++kk) {
        const short8 bf = *reinterpret_cast<const short8*>(
            gw2r + (size_t)(cc * 64 + 16 * ctt) * NH + kk * 32);
        z = __builtin_amdgcn_mfma_f32_16x16x32_bf16(af[kk], bf, z, 0, 0, 0);
      }
      const float bias = gb2_s[cc * 64 + 16 * ctt + r];
      float s = 0.f;
#pragma unroll
      for (int reg = 0; reg < 4; ++reg)
        s += 1.f / (1.f + __expf(-(z[reg] + bias)));
      s += __shfl_xor(s, 16);
      s += __shfl_xor(s, 32);
      if (lane < 16) atomicAdd(&gsum_s[cc * 64 + 16 * ctt + lane], s);
    }
  }
  __syncthreads();
  for (int i = t; i < NC; i += 256) {
    atomicAdd(&gsum_g[b * NC + i], gsum_s[i]);
    atomicAdd(&csum_g[b * NC + i], csum_s[i]);
  }
}

// ---------------- K3: finalize stats + affine MLP -> per-(b,c) y = A*x + D ----------------
__global__ __launch_bounds__(256) void k3_final(
    const float* __restrict__ xsum, const float* __restrict__ xsumsq,
    const float* __restrict__ csum, const float* __restrict__ gsum,
    const float* __restrict__ mw1, const float* __restrict__ mb1,
    const float* __restrict__ mw2, const float* __restrict__ mb2,
    float* __restrict__ a_arr, float* __restrict__ d_arr) {
  __shared__ __align__(16) float cp[NC];
  __shared__ __align__(16) float hm[NH];
  __shared__ float gbv[2 * NC];
  __shared__ double red[8];
  __shared__ float mu_l_s, sig_l_s;
  const int b = blockIdx.x, t = threadIdx.x;

  double s1 = 0.0, s2 = 0.0;
  for (int c = t; c < NC; c += 256) { s1 += (double)xsum[b * NC + c]; s2 += (double)xsumsq[b * NC + c]; }
  for (int off = 32; off; off >>= 1) { s1 += __shfl_down(s1, off); s2 += __shfl_down(s2, off); }
  if ((t & 63) == 0) { red[(t >> 6) * 2] = s1; red[(t >> 6) * 2 + 1] = s2; }
  for (int c = t; c < NC; c += 256) cp[c] = csum[b * NC + c] * (1.f / NL);
  __syncthreads();
  if (t == 0) {
    double S1 = red[0] + red[2] + red[4] + red[6];
    double S2 = red[1] + red[3] + red[5] + red[7];
    double n = (double)NC * NL;
    double mu = S1 / n;
    double var = S2 / n - mu * mu;
    mu_l_s = (float)mu;
    sig_l_s = (float)sqrt(var + (double)FEPS);
  }
  __syncthreads();
  if (t < NH) {
    const float4* row = reinterpret_cast<const float4*>(mw1 + (size_t)t * NC);
    const float4* cpv = reinterpret_cast<const float4*>(cp);
    float acc = mb1[t];
    for (int i = 0; i < NC / 4; ++i) {
      float4 wv = row[i], xv = cpv[i];
      acc += wv.x * xv.x + wv.y * xv.y + wv.z * xv.z + wv.w * xv.w;
    }
    hm[t] = fmaxf(acc, 0.f);
  }
  __syncthreads();
  for (int o = t; o < 2 * NC; o += 256) {
    const float4* row = reinterpret_cast<const float4*>(mw2 + (size_t)o * NH);
    const float4* hv = reinterpret_cast<const float4*>(hm);
    float acc = mb2[o];
    for (int i = 0; i < NH / 4; ++i) {
      float4 wv = row[i], xv = hv[i];
      acc += wv.x * xv.x + wv.y * xv.y + wv.z * xv.z + wv.w * xv.w;
    }
    gbv[o] = acc;
  }
  __syncthreads();
  const float mu_l = mu_l_s, sig_l = sig_l_s;
  for (int c = t; c < NC; c += 256) {
    float gm = gsum[b * NC + c] * (1.f / NL);
    double mu_c = (double)xsum[b * NC + c] / NL;
    double var_c = (double)xsumsq[b * NC + c] / NL - mu_c * mu_c;
    float sig_c = (float)sqrt(var_c + (double)FEPS);
    float mu = gm * (float)mu_c + (1.f - gm) * mu_l;
    float sg = gm * sig_c + (1.f - gm) * sig_l;
    float gamma = gbv[c], beta = gbv[NC + c];
    float A = (1.f + gamma) / sg;
    a_arr[b * NC + c] = A;
    d_arr[b * NC + c] = beta - A * mu;
  }
}

// ---------------- K4: y = A*x + D (x from L3 if retained), nt stores, imp = sum |y| ----------------
__global__ __launch_bounds__(256) void k4_y(
    const float* __restrict__ x, const float* __restrict__ a_arr,
    const float* __restrict__ d_arr, float* __restrict__ out, float* __restrict__ imp) {
  const int bc = blockIdx.x, t = threadIdx.x;
  const float A = a_arr[bc], D = d_arr[bc];
  const f32x4* xp = reinterpret_cast<const f32x4*>(x + (size_t)bc * NL);
  f32x4* op = reinterpret_cast<f32x4*>(out + (size_t)bc * NL);
  float s = 0.f;
#pragma unroll
  for (int i = 0; i < 8; ++i) {
    f32x4 v = __builtin_nontemporal_load(xp + i * 256 + t);   // last use of x
    f32x4 y;
    y.x = fmaf(A, v.x, D); y.y = fmaf(A, v.y, D);
    y.z = fmaf(A, v.z, D); y.w = fmaf(A, v.w, D);
    s += fabsf(y.x) + fabsf(y.y) + fabsf(y.z) + fabsf(y.w);
    __builtin_nontemporal_store(y, op + i * 256 + t);         // out never re-read
  }
  for (int off = 32; off; off >>= 1) s += __shfl_down(s, off);
  __shared__ float rs[4];
  if ((t & 63) == 0) rs[t >> 6] = s;
  __syncthreads();
  if (t == 0) imp[bc] = rs[0] + rs[1] + rs[2] + rs[3];
}

// ---------------- K5: fused top-k rank (jax.lax.top_k tie semantics) + zero dropped rows ----------------
__global__ __launch_bounds__(256) void k5_apply(
    const float* __restrict__ imp, float* __restrict__ out) {
  const int bc = blockIdx.x;
  const int b = bc >> 9;            // NC = 512
  const int c = bc & (NC - 1);
  const int t = threadIdx.x;
  const float* row = imp + b * NC;
  const float mine = row[c];
  int cnt = 0;
#pragma unroll
  for (int jj = 0; jj < 2; ++jj) {
    const int j = jj * 256 + t;
    const float o = row[j];
    cnt += (o > mine) || (o == mine && j < c);
  }
  for (int off = 32; off; off >>= 1) cnt += __shfl_down(cnt, off);
  __shared__ int rs[4];
  if ((t & 63) == 0) rs[t >> 6] = cnt;
  __syncthreads();
  const int rank = rs[0] + rs[1] + rs[2] + rs[3];   // block-uniform
  if (rank < NKEEP) return;
  f32x4* op = reinterpret_cast<f32x4*>(out + (size_t)bc * NL);
  const f32x4 z = (f32x4){0.f, 0.f, 0.f, 0.f};
#pragma unroll
  for (int i = 0; i < 8; ++i) __builtin_nontemporal_store(z, op + i * 256 + t);
}

extern "C" void kernel_launch(void* const* d_in, const int* in_sizes, int n_in,
                              void* d_out, int out_size, void* d_ws, size_t ws_size,
                              hipStream_t stream) {
  const float* x   = (const float*)d_in[0];
  const float* c   = (const float*)d_in[1];
  const float* gw1 = (const float*)d_in[2];
  const float* gb1 = (const float*)d_in[3];
  const float* gw2 = (const float*)d_in[4];
  const float* gb2 = (const float*)d_in[5];
  const float* mw1 = (const float*)d_in[6];
  const float* mb1 = (const float*)d_in[7];
  const float* mw2 = (const float*)d_in[8];
  const float* mb2 = (const float*)d_in[9];
  float* out = (float*)d_out;
  char* ws = (char*)d_ws;

  unsigned short* gw1b = (unsigned short*)(ws);             // 131072 B
  unsigned short* gw2b = (unsigned short*)(ws + 131072);    // 131072 B
  float* xsum   = (float*)(ws + 262144);
  float* xsumsq = (float*)(ws + 278528);
  float* csum   = (float*)(ws + 294912);
  float* gsum   = (float*)(ws + 311296);
  float* a_arr  = (float*)(ws + 327680);
  float* d_arr  = (float*)(ws + 344064);
  float* imp    = (float*)(ws + 360448);

  k1_xstats<<<NB * NC, 256, 0, stream>>>(x, xsum, xsumsq, gw1, gw2, gw1b, gw2b, csum, gsum);
  k2_gate<<<NB * (NL / 64), 256, 0, stream>>>(c, gw1b, gw2b, gb1, gb2, gsum, csum);
  k3_final<<<NB, 256, 0, stream>>>(xsum, xsumsq, csum, gsum, mw1, mb1, mw2, mb2, a_arr, d_arr);
  k4_y<<<NB * NC, 256, 0, stream>>>(x, a_arr, d_arr, out, imp);
  k5_apply<<<NB * NC, 256, 0, stream>>>(imp, out);
}